// Round 12
// baseline (572.284 us; speedup 1.0000x reference)
//
#include <hip/hip_runtime.h>
#include <hip/hip_bf16.h>
#include <stdint.h>

#define EPS 1e-3f

typedef __attribute__((ext_vector_type(8))) short bf16x8;
typedef __attribute__((ext_vector_type(4))) float f32x4;

__device__ inline uint32_t pk2(float a, float b) {
    __hip_bfloat162 p;
    p.x = __float2bfloat16(a);
    p.y = __float2bfloat16(b);
    return *(uint32_t*)&p;
}

// ---------------------------------------------------------------------------
// k0: all preps in ONE dispatch.
//  blocks 0..3599   : At_g[k][t][w32][v32] = bf16(A[k][t][v][w]) (zero-padded)
//  blocks 3600..3879: W1t / Abf / csA_g
// ---------------------------------------------------------------------------
__global__ __launch_bounds__(256) void k0_prep(
    const float* __restrict__ W1, const float* __restrict__ Wt,
    const float* __restrict__ A,
    uint16_t* __restrict__ W1t, uint16_t* __restrict__ Abf,
    float* __restrict__ csA_g, uint16_t* __restrict__ At_g)
{
    const int b = blockIdx.x;
    if (b < 3600) {
        int i = b * 256 + threadIdx.x;
        int v = i & 31, w = (i >> 5) & 31, rest = i >> 10;
        int t = rest % 300, k = rest / 300;
        float val = 0.f;
        if (v < 25 && w < 25)
            val = A[((k * 300 + t) * 25 + v) * 25 + w];
        __hip_bfloat16 bb = __float2bfloat16(val);
        At_g[i] = *(uint16_t*)&bb;
    } else {
        int i = (b - 3600) * 256 + threadIdx.x;
        if (i < 12288) {
            int f = i / 192, Kp = i % 192, k = Kp >> 6, c = Kp & 63;
            __hip_bfloat16 bb = __float2bfloat16(W1[c * 192 + k * 64 + f]);
            W1t[i] = *(uint16_t*)&bb;
        } else if (i < 49152) {
            int j = i - 12288;
            int jj = j & 7, fo = (j >> 3) & 63, kb = j >> 9;
            int kk = kb * 8 + jj, dt = kk >> 6, fi = kk & 63;
            __hip_bfloat16 bb = __float2bfloat16(Wt[(dt * 64 + fi) * 64 + fo]);
            Abf[j] = *(uint16_t*)&bb;
        } else if (i < 71652) {
            int j = i - 49152;
            int k = j / 7500, r = j % 7500;
            int t = r / 25, w = r % 25;
            float s = 0.f;
            for (int v = 0; v < 25; ++v)
                s += A[((k * 300 + t) * 25 + v) * 25 + w];
            csA_g[j] = s;
        }
    }
}

// ---------------------------------------------------------------------------
// k1 v9 "deep wave": t-tile 20/block, 4 waves, each wave owns 5 SEQUENTIAL
//  t's with a software pipeline: GEMM-u(t_i) -> issue loads(t_{i+1}) ->
//  GEMM-z(t_i)+epilogue -> convert(t_{i+1}).  Slab (9.6 KB/wave) reused
//  across iterations (same-wave DS ops are in-order -> no barrier needed).
//  Grid 15x64 = 960 blocks (3,840 waves vs 19,200 in R9/R10).
// LDS: slabs 0..38399; s1 38400; b1n 38656; b1 38912..39679.
// ---------------------------------------------------------------------------
#define K1_SMEM 39680
__global__ __launch_bounds__(256, 4) void k1_wave(
    const float* __restrict__ x, const uint16_t* __restrict__ At_g,
    const uint16_t* __restrict__ W1t, const float* __restrict__ csA_g,
    const float* __restrict__ b1,
    const float* __restrict__ gamma1, const float* __restrict__ beta1,
    const float* __restrict__ mean1, const float* __restrict__ var1,
    uint32_t* __restrict__ h2u)
{
    extern __shared__ __align__(16) char smem[];
    float* s1s   = (float*)(smem + 38400);
    float* b1ns  = (float*)(smem + 38656);
    float* b1s   = (float*)(smem + 38912);

    const int t0   = blockIdx.x * 20;
    const int n    = blockIdx.y;
    const int tid  = threadIdx.x;
    const int lane = tid & 63, wv = tid >> 6;
    const int l15  = lane & 15, g = lane >> 4;
    const int tw0  = t0 + wv * 5;             // 15*20 = 300: no tail anywhere
    char* slab = smem + wv * 9600;

    // ---- epilogue constants; only barrier in the kernel ----
    if (tid < 64) {
        float rs = rsqrtf(var1[tid] + EPS);
        s1s[tid]  = gamma1[tid] * rs;
        b1ns[tid] = beta1[tid] - gamma1[tid] * mean1[tid] * rs;
    }
    if (tid >= 64 && tid < 256) b1s[tid - 64] = b1[tid - 64];
    __syncthreads();

    // ---- pipeline registers ----
    bf16x8 bfrN[6];
    float  xr8[4][8];
    float  x24v[4];
    bf16x8 aN[4];

    auto LOADT = [&](int t) {
        #pragma unroll
        for (int nf = 0; nf < 6; ++nf) {
            const int col = nf * 16 + l15;
            const int k = col >> 5, w = col & 31;
            bfrN[nf] = *(const bf16x8*)(At_g + (((k * 300 + t) * 32 + w) * 32 + g * 8));
        }
        const float* xb = x + (size_t)n * 480000 + t * 25;
        #pragma unroll
        for (int mf = 0; mf < 4; ++mf) {
            const int c = l15 + 16 * mf;
            const float* xr = xb + (size_t)c * 7500;
            if (g < 3) {
                const float* p = xr + g * 8;
                #pragma unroll
                for (int j = 0; j < 8; ++j) xr8[mf][j] = p[j];
            } else {
                x24v[mf] = xr[24];
            }
        }
    };
    auto CONV = [&]() {
        #pragma unroll
        for (int mf = 0; mf < 4; ++mf) {
            union { bf16x8 v; uint32_t u[4]; } ua;
            if (g < 3) {
                ua.u[0] = pk2(xr8[mf][0], xr8[mf][1]);
                ua.u[1] = pk2(xr8[mf][2], xr8[mf][3]);
                ua.u[2] = pk2(xr8[mf][4], xr8[mf][5]);
                ua.u[3] = pk2(xr8[mf][6], xr8[mf][7]);
            } else {        // v = 24 real; v = 25..31 zero (B rows zeroed too)
                ua.u[0] = pk2(x24v[mf], 0.f);
                ua.u[1] = 0; ua.u[2] = 0; ua.u[3] = 0;
            }
            aN[mf] = ua.v;
        }
    };

    LOADT(tw0);
    CONV();

    #pragma unroll
    for (int i = 0; i < 5; ++i) {
        const int t = tw0 + i;

        // ---- GEMM-u (2 halves of 3 nf) -> slab ----
        #pragma unroll
        for (int hh = 0; hh < 2; ++hh) {
            f32x4 acc[4][3];
            #pragma unroll
            for (int mf = 0; mf < 4; ++mf)
                #pragma unroll
                for (int nf3 = 0; nf3 < 3; ++nf3)
                    acc[mf][nf3] = (f32x4){0.f, 0.f, 0.f, 0.f};

            #pragma unroll
            for (int nf3 = 0; nf3 < 3; ++nf3) {
                const int nf = hh * 3 + nf3;
                acc[0][nf3] = __builtin_amdgcn_mfma_f32_16x16x32_bf16(aN[0], bfrN[nf], acc[0][nf3], 0, 0, 0);
                acc[1][nf3] = __builtin_amdgcn_mfma_f32_16x16x32_bf16(aN[1], bfrN[nf], acc[1][nf3], 0, 0, 0);
                acc[2][nf3] = __builtin_amdgcn_mfma_f32_16x16x32_bf16(aN[2], bfrN[nf], acc[2][nf3], 0, 0, 0);
                acc[3][nf3] = __builtin_amdgcn_mfma_f32_16x16x32_bf16(aN[3], bfrN[nf], acc[3][nf3], 0, 0, 0);
            }

            #pragma unroll
            for (int nf3 = 0; nf3 < 3; ++nf3) {
                const int col = (hh * 3 + nf3) * 16 + l15;
                const int k = col >> 5, w = col & 31;
                if (w < 25) {
                    const int sw = (w & 7) << 4;
                    #pragma unroll
                    for (int mf = 0; mf < 4; ++mf) {
                        const int c0 = mf * 16 + g * 4;
                        const int off = w * 384 + (((k * 64 + c0) * 2) ^ sw);
                        uint2 val;
                        val.x = pk2(acc[mf][nf3][0], acc[mf][nf3][1]);
                        val.y = pk2(acc[mf][nf3][2], acc[mf][nf3][3]);
                        *(uint2*)(slab + off) = val;
                    }
                }
            }
        }

        // ---- issue next-t global loads (overlap the z-GEMM below) ----
        if (i < 4) LOADT(t + 1);

        // ---- GEMM-z from slab (same-wave DS is in-order: no wait needed) ----
        f32x4 accz[4][2];
        #pragma unroll
        for (int mf = 0; mf < 4; ++mf)
            #pragma unroll
            for (int q = 0; q < 2; ++q)
                accz[mf][q] = (f32x4){0.f, 0.f, 0.f, 0.f};

        int qaddr[2], qswz[2];
        #pragma unroll
        for (int q = 0; q < 2; ++q) {
            int w = q * 16 + l15;
            int wc = (w < 25) ? w : 24;       // clamp keeps ds_read in slab
            qaddr[q] = wc * 384;
            qswz[q]  = (wc & 7) << 4;
        }

        #pragma unroll
        for (int kb = 0; kb < 6; ++kb) {
            bf16x8 az[4];
            #pragma unroll
            for (int mf = 0; mf < 4; ++mf)
                az[mf] = *(const bf16x8*)(W1t + (l15 + 16 * mf) * 192 + kb * 32 + g * 8);
            #pragma unroll
            for (int q = 0; q < 2; ++q) {
                bf16x8 b = *(const bf16x8*)(slab + qaddr[q] + ((kb * 64 + g * 16) ^ qswz[q]));
                accz[0][q] = __builtin_amdgcn_mfma_f32_16x16x32_bf16(az[0], b, accz[0][q], 0, 0, 0);
                accz[1][q] = __builtin_amdgcn_mfma_f32_16x16x32_bf16(az[1], b, accz[1][q], 0, 0, 0);
                accz[2][q] = __builtin_amdgcn_mfma_f32_16x16x32_bf16(az[2], b, accz[2][q], 0, 0, 0);
                accz[3][q] = __builtin_amdgcn_mfma_f32_16x16x32_bf16(az[3], b, accz[3][q], 0, 0, 0);
            }
        }

        // ---- epilogue: +bias(csA), BN1, ReLU, pack, store h2 ----
        const uint32_t tb = (uint32_t)(n * 300 + t);
        #pragma unroll
        for (int q = 0; q < 2; ++q) {
            const int w = q * 16 + l15;
            if (w < 25) {
                const int ci = t * 25 + w;
                const float cs0 = csA_g[ci];
                const float cs1 = csA_g[7500 + ci];
                const float cs2 = csA_g[15000 + ci];
                const uint32_t rowbase = tb * 800 + w * 32;
                #pragma unroll
                for (int mf = 0; mf < 4; ++mf) {
                    const int f0 = mf * 16 + g * 4;
                    float zz[4];
                    #pragma unroll
                    for (int rg = 0; rg < 4; ++rg) {
                        const int f = f0 + rg;
                        float z = accz[mf][q][rg]
                                + b1s[f] * cs0 + b1s[64 + f] * cs1
                                + b1s[128 + f] * cs2;
                        z = z * s1s[f] + b1ns[f];
                        zz[rg] = fmaxf(z, 0.f);
                    }
                    uint2 st;
                    st.x = pk2(zz[0], zz[1]);
                    st.y = pk2(zz[2], zz[3]);
                    *(uint2*)(h2u + rowbase + (f0 >> 1)) = st;
                }
            }
        }

        // ---- convert next t's x (waits its loads; frees xr8 for reuse) ----
        if (i < 4) CONV();
    }
}

// ---------------------------------------------------------------------------
// k2 v3 (unchanged from R10): operand-swapped temporal conv GEMM, forced-MLP
//  staging, Wt rotation, batched epilogue x-loads.
// ---------------------------------------------------------------------------
#define K2_SMEM 51712
__global__ __launch_bounds__(256, 3) void k2_mfma(
    const char* __restrict__ h2b,
    const uint16_t* __restrict__ Abf,
    const float* __restrict__ bt,
    const float* __restrict__ gamma2, const float* __restrict__ beta2,
    const float* __restrict__ mean2,  const float* __restrict__ var2,
    const float* __restrict__ x,
    float* __restrict__ out)
{
    extern __shared__ __align__(16) char smem2[];
    char*  lds_h = smem2;
    float* s2s   = (float*)(smem2 + 51200);
    float* b2s   = s2s + 64;

    const int t0  = blockIdx.x * 8;
    const int n   = blockIdx.y;
    const int tid = threadIdx.x;

    const size_t hn = (size_t)n * 300 * 3200;
    int4 tmp[13];
    #pragma unroll
    for (int i = 0; i < 13; ++i) {
        const int c = tid + i * 256;
        tmp[i] = make_int4(0, 0, 0, 0);
        if (c < 3200) {
            int rr = c >> 3, c8 = c & 7;
            int trow = rr / 25;
            int w = rr - trow * 25;
            int tg = t0 - 4 + trow;
            if (tg >= 0 && tg < 300)
                tmp[i] = *(const int4*)(h2b + hn + (size_t)tg * 3200 + w * 128 + (c8 << 4));
        }
    }
    __builtin_amdgcn_sched_barrier(0);

    if (tid < 64) {
        float rs = rsqrtf(var2[tid] + EPS);
        float s  = gamma2[tid] * rs;
        s2s[tid] = s;
        b2s[tid] = beta2[tid] - gamma2[tid] * mean2[tid] * rs + bt[tid] * s;
    }

    #pragma unroll
    for (int i = 0; i < 13; ++i) {
        const int c = tid + i * 256;
        if (c < 3200) {
            int s = c << 4;
            *(int4*)(lds_h + (s ^ (((s >> 7) & 7) << 4))) = tmp[i];
        }
    }
    __syncthreads();

    const int wv = tid >> 6, lane = tid & 63;
    const int l15 = lane & 15, g = lane >> 4;
    const int nMf = (wv == 0) ? 4 : 3;

    int rbase[4];
    #pragma unroll
    for (int q = 0; q < 4; ++q) {
        int col = (q * 4 + wv) * 16 + l15;
        rbase[q] = (col < 200) ? col : 199;
    }

    f32x4 acc[4][4];
    #pragma unroll
    for (int q = 0; q < 4; ++q)
        #pragma unroll
        for (int mf = 0; mf < 4; ++mf)
            acc[q][mf] = (f32x4){0.f, 0.f, 0.f, 0.f};

    bf16x8 wc_[4];
    #pragma unroll
    for (int mf = 0; mf < 4; ++mf)
        wc_[mf] = *(const bf16x8*)(Abf + ((0 * 4 + g) * 64 + l15 + mf * 16) * 8);

    for (int kk = 0; kk < 18; ++kk) {
        const int dt   = kk >> 1;
        const int half = (kk & 1) << 6;
        bf16x8 wn_[4];
        if (kk < 17) {
            const int kbn = (kk + 1) * 4 + g;
            #pragma unroll
            for (int mf = 0; mf < 4; ++mf)
                wn_[mf] = *(const bf16x8*)(Abf + (kbn * 64 + l15 + mf * 16) * 8);
        }
        #pragma unroll
        for (int q = 0; q < 4; ++q) {
            if (q < nMf) {
                int r = rbase[q] + 25 * dt;
                int s = (r << 7) + half + (g << 4);
                bf16x8 hfr = *(const bf16x8*)(lds_h + (s ^ ((r & 7) << 4)));
                acc[q][0] = __builtin_amdgcn_mfma_f32_16x16x32_bf16(hfr, wc_[0], acc[q][0], 0, 0, 0);
                acc[q][1] = __builtin_amdgcn_mfma_f32_16x16x32_bf16(hfr, wc_[1], acc[q][1], 0, 0, 0);
                acc[q][2] = __builtin_amdgcn_mfma_f32_16x16x32_bf16(hfr, wc_[2], acc[q][2], 0, 0, 0);
                acc[q][3] = __builtin_amdgcn_mfma_f32_16x16x32_bf16(hfr, wc_[3], acc[q][3], 0, 0, 0);
            }
        }
        if (kk < 17) {
            #pragma unroll
            for (int mf = 0; mf < 4; ++mf) wc_[mf] = wn_[mf];
        }
    }

    const size_t outn = (size_t)n * 480000;
    const int base = t0 * 25;
    const int vcols = (7500 - base < 200) ? (7500 - base) : 200;

    float4 xrv[4][4];
    #pragma unroll
    for (int q = 0; q < 4; ++q) {
        const int col0 = (q * 4 + wv) * 16 + g * 4;
        if (q < nMf && col0 < vcols) {
            #pragma unroll
            for (int mf = 0; mf < 4; ++mf) {
                const int fo = mf * 16 + l15;
                xrv[q][mf] = *(const float4*)(x + outn + (size_t)fo * 7500 + base + col0);
            }
        }
    }
    __builtin_amdgcn_sched_barrier(0);

    #pragma unroll
    for (int q = 0; q < 4; ++q) {
        const int col0 = (q * 4 + wv) * 16 + g * 4;
        if (q < nMf && col0 < vcols) {
            #pragma unroll
            for (int mf = 0; mf < 4; ++mf) {
                const int fo = mf * 16 + l15;
                const size_t ga = outn + (size_t)fo * 7500 + base + col0;
                const float s2 = s2s[fo], b2 = b2s[fo];
                float4 o;
                o.x = fmaxf(acc[q][mf][0] * s2 + b2 + xrv[q][mf].x, 0.f);
                o.y = fmaxf(acc[q][mf][1] * s2 + b2 + xrv[q][mf].y, 0.f);
                o.z = fmaxf(acc[q][mf][2] * s2 + b2 + xrv[q][mf].z, 0.f);
                o.w = fmaxf(acc[q][mf][3] * s2 + b2 + xrv[q][mf].w, 0.f);
                *(float4*)(out + ga) = o;
            }
        }
    }
}

// ---------------------------------------------------------------------------
extern "C" void kernel_launch(void* const* d_in, const int* in_sizes, int n_in,
                              void* d_out, int out_size, void* d_ws, size_t ws_size,
                              hipStream_t stream) {
    const float* x      = (const float*)d_in[0];
    const float* W1     = (const float*)d_in[1];
    const float* b1     = (const float*)d_in[2];
    const float* A      = (const float*)d_in[3];
    const float* gamma1 = (const float*)d_in[4];
    const float* beta1  = (const float*)d_in[5];
    const float* mean1  = (const float*)d_in[6];
    const float* var1   = (const float*)d_in[7];
    const float* Wt     = (const float*)d_in[8];
    const float* bt     = (const float*)d_in[9];
    const float* gamma2 = (const float*)d_in[10];
    const float* beta2  = (const float*)d_in[11];
    const float* mean2  = (const float*)d_in[12];
    const float* var2   = (const float*)d_in[13];
    float* out = (float*)d_out;

    // ws layout (bytes):
    //   h2   : 0          .. 61,440,000   bf16 [64][300][25][64]
    //   At_g : 61,440,000 .. 63,283,200   bf16 [3][300][32][32]
    //   W1t  : 63,283,200 .. 63,307,776   bf16 [64][192]
    //   Abf  : 63,307,776 .. 63,381,504   bf16 Wt frags
    //   csA_g: 63,381,504 .. 63,471,504   f32  [3][7500]
    char* ws = (char*)d_ws;
    uint32_t* h2u   = (uint32_t*)ws;
    char*     h2b   = ws;
    uint16_t* At_g  = (uint16_t*)(ws + 61440000);
    uint16_t* W1t   = (uint16_t*)(ws + 63283200);
    uint16_t* Abf   = (uint16_t*)(ws + 63307776);
    float*    csA_g = (float*)   (ws + 63381504);

    hipFuncSetAttribute((const void*)k1_wave,
                        hipFuncAttributeMaxDynamicSharedMemorySize, K1_SMEM);
    hipFuncSetAttribute((const void*)k2_mfma,
                        hipFuncAttributeMaxDynamicSharedMemorySize, K2_SMEM);

    k0_prep<<<3880, 256, 0, stream>>>(W1, Wt, A, W1t, Abf, csA_g, At_g);
    k1_wave<<<dim3(15, 64), 256, K1_SMEM, stream>>>(
        x, At_g, W1t, csA_g, b1, gamma1, beta1, mean1, var1, h2u);
    k2_mfma<<<dim3(38, 64), 256, K2_SMEM, stream>>>(
        h2b, Abf, bt, gamma2, beta2, mean2, var2, x, out);
}